// Round 4
// baseline (1553.030 us; speedup 1.0000x reference)
//
#include <hip/hip_runtime.h>

// ---------------------------------------------------------------------------
// NeighborEmbedder on MI355X (gfx950). Round 4: gemm8 rewritten as a register
// software pipeline: reads for quadrant q+1 issue in phase q (counted lgkm by
// compiler), staging for kt+2 in P3/P4, single counted vmcnt(0) per kt.
// ---------------------------------------------------------------------------

typedef unsigned short u16;
typedef u16   u16x8 __attribute__((ext_vector_type(8)));
typedef u16   u16x4 __attribute__((ext_vector_type(4)));
typedef __bf16 bf16x8 __attribute__((ext_vector_type(8)));
typedef float f32x4 __attribute__((ext_vector_type(4)));

static __device__ __forceinline__ u16 f2bf(float f) {
  union { float f; unsigned u; } v; v.f = f;
  unsigned r = v.u + 0x7FFFu + ((v.u >> 16) & 1u);   // RNE
  return (u16)(r >> 16);
}
static __device__ __forceinline__ float bf2f(u16 u) {
  union { unsigned u; float f; } v; v.u = ((unsigned)u) << 16;
  return v.f;
}

static __device__ __forceinline__ void gld16(const void* g, void* l) {
  __builtin_amdgcn_global_load_lds(
      (__attribute__((address_space(1))) unsigned int*)(size_t)g,
      (__attribute__((address_space(3))) unsigned int*)(unsigned)(size_t)l,
      16, 0, 0);
}

static __device__ __forceinline__ int xcd_swz(int bid, int nwg) {
  int q = nwg >> 3, r = nwg & 7;
  int xcd = bid & 7, sub = bid >> 3;
  return (xcd < r ? xcd * (q + 1) : r * (q + 1) + (xcd - r) * q) + sub;
}

#define BAR   __builtin_amdgcn_s_barrier()
#define PRIO1 __builtin_amdgcn_s_setprio(1)
#define PRIO0 __builtin_amdgcn_s_setprio(0)
#define VM0   asm volatile("s_waitcnt vmcnt(0)" ::: "memory")
#define VM8   asm volatile("s_waitcnt vmcnt(8)" ::: "memory")

// ---------------------------------------------------------------------------
// gemm8: out[M,N](bf16) = A[M,K](bf16) @ W[N,K]^T + bias (+pos/+res/gelu)
// 256x256 tile, BK=64, 512 threads = 8 waves (2M x 4N), per-wave 128x64 out.
// Register pipeline: phase q issues ds_reads for quadrant q+1; compiler emits
// counted lgkmcnt so LDS transfer overlaps MFMA. Staging for kt+2 in P3/P4,
// vmcnt(0) once per kt (stages ~6 phases old). XOR-swizzled LDS (T2).
// Requires M%256==0, N%256==0, K%128==0.
// ---------------------------------------------------------------------------
template<bool HAS_POS, bool HAS_RES, bool HAS_GELU>
__global__ __launch_bounds__(512, 2) void gemm8(
    const u16* __restrict__ A, int lda,
    const u16* __restrict__ W,
    const float* __restrict__ bias,
    const float* __restrict__ pos,
    const u16* res, int res_stride,
    u16* out,
    int M, int N, int K, int nbx)
{
  __shared__ u16 As[2][2][128][64];   // [dbuf][half(M)][row][k]
  __shared__ u16 Bs[2][2][128][64];   // [dbuf][half(N)][row][k]

  const int t    = threadIdx.x;
  const int lane = t & 63, wv = t >> 6;
  const int swz  = xcd_swz(blockIdx.x, gridDim.x);
  const int bm   = (swz / nbx) * 256, bn = (swz % nbx) * 256;
  const int wr   = wv >> 2, wc = wv & 3;      // wave grid 2(M) x 4(N)

  // staging lane geometry (physical-linear LDS, pre-swizzled global col)
  const int stg_r = (wv << 3) + (lane >> 3);                 // 0..63
  const int stg_c = (((lane & 7) ^ (lane >> 3)) << 3);       // swizzled col
  // ds_read lane geometry
  const int lr  = lane & 15;
  const int kgb = (lane >> 4) << 4;                          // 16B k-group
  const int swz16 = (lr & 7) << 4;                           // XOR byte mask

  const char* Ab[2] = { (const char*)&As[0][wr][0][0], (const char*)&As[1][wr][0][0] };
  const char* Bb[2] = { (const char*)&Bs[0][wc >> 1][0][0], (const char*)&Bs[1][wc >> 1][0][0] };
  const int bro = (wc & 1) * 64;

  f32x4 acc[8][4] = {};
  bf16x8 A0[4][2], A1[4][2], B0[2][2], B1[2][2];

  auto stage_A = [&](int d, int kt) {    // both M-halves: 4 gld16
    #pragma unroll
    for (int h = 0; h < 2; ++h) {
      const u16* gp = A + (size_t)(bm + h * 128 + stg_r) * lda + kt * 64 + stg_c;
      gld16(gp,                    &As[d][h][(wv << 3)][0]);
      gld16(gp + (size_t)64 * lda, &As[d][h][(wv << 3) + 64][0]);
    }
  };
  auto stage_B = [&](int d, int kt) {    // both N-halves: 4 gld16
    #pragma unroll
    for (int h = 0; h < 2; ++h) {
      const u16* gp = W + (size_t)(bn + h * 128 + stg_r) * K + kt * 64 + stg_c;
      gld16(gp,                  &Bs[d][h][(wv << 3)][0]);
      gld16(gp + (size_t)64 * K, &Bs[d][h][(wv << 3) + 64][0]);
    }
  };
  auto read_A = [&](bf16x8 (&dst)[4][2], int mh, int d) {   // 8 x b128
    #pragma unroll
    for (int m = 0; m < 4; ++m)
      #pragma unroll
      for (int ks = 0; ks < 2; ++ks)
        dst[m][ks] = *(const bf16x8*)(Ab[d] + ((mh * 64 + m * 16 + lr) << 7)
                                            + (((ks << 6) | kgb) ^ swz16));
  };
  auto read_B = [&](bf16x8 (&dst)[2][2], int nh, int d) {   // 4 x b128
    #pragma unroll
    for (int n = 0; n < 2; ++n)
      #pragma unroll
      for (int ks = 0; ks < 2; ++ks)
        dst[n][ks] = *(const bf16x8*)(Bb[d] + ((bro + nh * 32 + n * 16 + lr) << 7)
                                            + (((ks << 6) | kgb) ^ swz16));
  };
  auto mfma_q = [&](bf16x8 (&aa)[4][2], int mh, bf16x8 (&bb)[2][2], int nh) {
    #pragma unroll
    for (int m = 0; m < 4; ++m)
      #pragma unroll
      for (int nn = 0; nn < 2; ++nn)
        #pragma unroll
        for (int ks = 0; ks < 2; ++ks)
          acc[mh * 4 + m][nh * 2 + nn] = __builtin_amdgcn_mfma_f32_16x16x32_bf16(
              aa[m][ks], bb[nn][ks], acc[mh * 4 + m][nh * 2 + nn], 0, 0, 0);
  };

  // ---- prologue: stage kt0 -> buf0, kt1 -> buf1; wait only kt0's 8 loads
  stage_A(0, 0); stage_B(0, 0);
  stage_A(1, 1); stage_B(1, 1);
  VM8; BAR;
  read_A(A0, 0, 0);          // pre-read for kt0.Q00
  read_B(B0, 0, 0);

  const int nkt = K >> 6;
  for (int kt = 0; kt < nkt; ++kt) {
    const int d   = kt & 1;
    const bool pf  = (kt + 1 < nkt);
    const bool pf2 = (kt + 2 < nkt);
    // P1: reads for Q01
    read_B(B1, 1, d);
    BAR;
    PRIO1; mfma_q(A0, 0, B0, 0); PRIO0;   // Q00
    BAR;
    // P2: reads for Q10
    read_A(A1, 1, d);
    BAR;
    PRIO1; mfma_q(A0, 0, B1, 1); PRIO0;   // Q01
    VM0;                                   // buf d^1 (kt+1) staged long ago
    BAR;
    // P3: reads for kt+1.Q00 (A part); stage A(kt+2) -> buf d
    if (pf)  read_A(A0, 0, d ^ 1);
    if (pf2) stage_A(d, kt + 2);
    BAR;
    PRIO1; mfma_q(A1, 1, B0, 0); PRIO0;   // Q10
    BAR;
    // P4: reads for kt+1.Q00 (B part); stage B(kt+2) -> buf d
    if (pf)  read_B(B0, 0, d ^ 1);
    if (pf2) stage_B(d, kt + 2);
    BAR;
    PRIO1; mfma_q(A1, 1, B1, 1); PRIO0;   // Q11
    BAR;
  }

  // ---- epilogue: row=(lane>>4)*4+r (+m*16), col=lane&15 (+n*16)  [m89]
  const int lq = lane >> 4;
  #pragma unroll
  for (int m = 0; m < 8; ++m) {
    #pragma unroll
    for (int n = 0; n < 4; ++n) {
      int col = bn + wc * 64 + n * 16 + lr;
      float bv = bias[col];
      #pragma unroll
      for (int r = 0; r < 4; ++r) {
        int row = bm + wr * 128 + m * 16 + lq * 4 + r;
        float v = acc[m][n][r] + bv;
        if constexpr (HAS_POS) v += pos[(row % 9) * 512 + col];
        if constexpr (HAS_RES) v += bf2f(res[(size_t)row * res_stride + col]);
        if constexpr (HAS_GELU) v = 0.5f * v * (1.f + erff(v * 0.70710678118f));
        out[(size_t)row * N + col] = f2bf(v);
      }
    }
  }
}

// ---------------------------------------------------------------------------
// gemm_k: 128x128 tile, 256 threads (kept for the M=8192, N=512 GEMMs)
// ---------------------------------------------------------------------------
template<bool HAS_RES, bool HAS_GELU>
__global__ __launch_bounds__(256) void gemm_k(
    const u16* __restrict__ A, int lda,
    const u16* __restrict__ W,
    const float* __restrict__ bias,
    const u16* res, int res_stride,
    u16* out,
    int M, int N, int K, int nbx)
{
  __shared__ u16 As[128 * 32];
  __shared__ u16 Bs[128 * 32];
  const int t    = threadIdx.x;
  const int lane = t & 63, wv = t >> 6;
  const int swz  = xcd_swz(blockIdx.x, gridDim.x);
  const int bm   = (swz / nbx) * 128, bn = (swz % nbx) * 128;
  const int wr   = wv >> 1, wc = wv & 1;

  f32x4 acc[4][4] = {};
  const int srow = lane >> 2, skk = (lane & 3) * 8;

  for (int k0 = 0; k0 < K; k0 += 32) {
    __syncthreads();
    gld16(A + (size_t)(bm + wv * 16 + srow) * lda + k0 + skk, &As[wv * 512]);
    gld16(A + (size_t)(bm + (wv + 4) * 16 + srow) * lda + k0 + skk, &As[(wv + 4) * 512]);
    gld16(W + (size_t)(bn + wv * 16 + srow) * K + k0 + skk, &Bs[wv * 512]);
    gld16(W + (size_t)(bn + (wv + 4) * 16 + srow) * K + k0 + skk, &Bs[(wv + 4) * 512]);
    __syncthreads();

    const int lr = lane & 15, lk = (lane >> 4) * 8;
    bf16x8 a[4], b[4];
    #pragma unroll
    for (int m = 0; m < 4; ++m)
      a[m] = *(const bf16x8*)&As[(wr * 64 + m * 16 + lr) * 32 + lk];
    #pragma unroll
    for (int n = 0; n < 4; ++n)
      b[n] = *(const bf16x8*)&Bs[(wc * 64 + n * 16 + lr) * 32 + lk];
    #pragma unroll
    for (int m = 0; m < 4; ++m)
      #pragma unroll
      for (int n = 0; n < 4; ++n)
        acc[m][n] = __builtin_amdgcn_mfma_f32_16x16x32_bf16(a[m], b[n], acc[m][n], 0, 0, 0);
  }

  const int lr = lane & 15, lq = lane >> 4;
  #pragma unroll
  for (int m = 0; m < 4; ++m) {
    #pragma unroll
    for (int n = 0; n < 4; ++n) {
      int col = bn + wc * 64 + n * 16 + lr;
      float bv = bias[col];
      #pragma unroll
      for (int r = 0; r < 4; ++r) {
        int row = bm + wr * 64 + m * 16 + lq * 4 + r;
        float v = acc[m][n][r] + bv;
        if constexpr (HAS_RES) v += bf2f(res[(size_t)row * res_stride + col]);
        if constexpr (HAS_GELU) v = 0.5f * v * (1.f + erff(v * 0.70710678118f));
        out[(size_t)row * N + col] = f2bf(v);
      }
    }
  }
}

// ---------------------------------------------------------------------------
// LayerNorm over rows of 512 (bf16 in). One wave per row, 4 rows per block.
// ---------------------------------------------------------------------------
__global__ __launch_bounds__(256) void ln_k(
    const u16* in,
    const float* __restrict__ g, const float* __restrict__ be,
    u16* out_bf, float* out_f32, int rows)
{
  int wv = threadIdx.x >> 6, lane = threadIdx.x & 63;
  int row = blockIdx.x * 4 + wv;
  if (row >= rows) return;
  const u16* p = in + (size_t)row * 512;
  u16x8 v = *(const u16x8*)&p[lane * 8];
  float x[8], s = 0.f, sq = 0.f;
  #pragma unroll
  for (int j = 0; j < 8; ++j) { x[j] = bf2f(v[j]); s += x[j]; sq += x[j] * x[j]; }
  #pragma unroll
  for (int o = 32; o > 0; o >>= 1) { s += __shfl_xor(s, o, 64); sq += __shfl_xor(sq, o, 64); }
  float mean = s * (1.f / 512.f);
  float var  = sq * (1.f / 512.f) - mean * mean;
  float rs   = rsqrtf(var + 1e-5f);
  float y[8];
  #pragma unroll
  for (int j = 0; j < 8; ++j) {
    int c = lane * 8 + j;
    y[j] = (x[j] - mean) * rs * g[c] + be[c];
  }
  if (out_bf) {
    u16x8 o8;
    #pragma unroll
    for (int j = 0; j < 8; ++j) o8[j] = f2bf(y[j]);
    *(u16x8*)&out_bf[(size_t)row * 512 + lane * 8] = o8;
  }
  if (out_f32) {
    #pragma unroll
    for (int j = 0; j < 8; ++j) out_f32[(size_t)row * 512 + lane * 8 + j] = y[j];
  }
}

// ---------------------------------------------------------------------------
// Self-attention, one block per sample: qkv[9,1536] (q|k|v), H=8, d=64, L=9.
// ---------------------------------------------------------------------------
__global__ __launch_bounds__(256) void sa_attn_k(const u16* __restrict__ qkv,
                                                 u16* __restrict__ out)
{
  __shared__ u16  s_qkv[9 * 1536];
  __shared__ float s_sc[8][81];
  const int s = blockIdx.x, t = threadIdx.x;
  const u16* src = qkv + (size_t)s * 9 * 1536;
  for (int i = t; i < (9 * 1536) / 8; i += 256)
    *(u16x8*)&s_qkv[i * 8] = *(const u16x8*)&src[i * 8];
  __syncthreads();

  const int h = t >> 5, sl = t & 31;
  for (int p = sl; p < 81; p += 32) {
    int qi = p / 9, ki = p % 9;
    const u16* qp = &s_qkv[qi * 1536 + h * 64];
    const u16* kp = &s_qkv[ki * 1536 + 512 + h * 64];
    float d = 0.f;
    #pragma unroll
    for (int e8 = 0; e8 < 8; ++e8) {
      u16x8 qv = *(const u16x8*)&qp[e8 * 8];
      u16x8 kv = *(const u16x8*)&kp[e8 * 8];
      #pragma unroll
      for (int j = 0; j < 8; ++j) d += bf2f(qv[j]) * bf2f(kv[j]);
    }
    s_sc[h][p] = d * 0.125f;
  }
  __syncthreads();

  if (t < 72) {
    int hh = t / 9, qi = t % 9;
    float* sc = &s_sc[hh][qi * 9];
    float mx = sc[0];
    #pragma unroll
    for (int i = 1; i < 9; ++i) mx = fmaxf(mx, sc[i]);
    float e[9], sum = 0.f;
    #pragma unroll
    for (int i = 0; i < 9; ++i) { e[i] = __expf(sc[i] - mx); sum += e[i]; }
    float inv = 1.f / sum;
    #pragma unroll
    for (int i = 0; i < 9; ++i) sc[i] = e[i] * inv;
  }
  __syncthreads();

  for (int gidx = sl; gidx < 72; gidx += 32) {
    int qi = gidx >> 3, dg = gidx & 7;
    float a[8] = {};
    #pragma unroll
    for (int ki = 0; ki < 9; ++ki) {
      float pr = s_sc[h][qi * 9 + ki];
      u16x8 vv = *(const u16x8*)&s_qkv[ki * 1536 + 1024 + h * 64 + dg * 8];
      #pragma unroll
      for (int j = 0; j < 8; ++j) a[j] += pr * bf2f(vv[j]);
    }
    u16x8 o8;
    #pragma unroll
    for (int j = 0; j < 8; ++j) o8[j] = f2bf(a[j]);
    *(u16x8*)&out[((size_t)s * 9 + qi) * 512 + h * 64 + dg * 8] = o8;
  }
}

// ---------------------------------------------------------------------------
// Cross-attention, one block per sample: q[512], kv[9,1024] (k|v).
// ---------------------------------------------------------------------------
__global__ __launch_bounds__(256) void ca_attn_k(const u16* __restrict__ q,
                                                 const u16* __restrict__ kv,
                                                 u16* __restrict__ out)
{
  __shared__ u16  s_q[512];
  __shared__ u16  s_kv[9 * 1024];
  __shared__ float s_sc[8][9];
  const int s = blockIdx.x, t = threadIdx.x;
  if (t < 64) *(u16x8*)&s_q[t * 8] = *(const u16x8*)&q[(size_t)s * 512 + t * 8];
  for (int i = t; i < (9 * 1024) / 8; i += 256)
    *(u16x8*)&s_kv[i * 8] = *(const u16x8*)&kv[(size_t)s * 9 * 1024 + i * 8];
  __syncthreads();

  if (t < 72) {
    int h = t / 9, ki = t % 9;
    const u16* qp = &s_q[h * 64];
    const u16* kp = &s_kv[ki * 1024 + h * 64];
    float d = 0.f;
    #pragma unroll
    for (int e8 = 0; e8 < 8; ++e8) {
      u16x8 qv = *(const u16x8*)&qp[e8 * 8];
      u16x8 kvv = *(const u16x8*)&kp[e8 * 8];
      #pragma unroll
      for (int j = 0; j < 8; ++j) d += bf2f(qv[j]) * bf2f(kvv[j]);
    }
    s_sc[h][ki] = d * 0.125f;
  }
  __syncthreads();

  if (t < 8) {
    float* sc = s_sc[t];
    float mx = sc[0];
    #pragma unroll
    for (int i = 1; i < 9; ++i) mx = fmaxf(mx, sc[i]);
    float e[9], sum = 0.f;
    #pragma unroll
    for (int i = 0; i < 9; ++i) { e[i] = __expf(sc[i] - mx); sum += e[i]; }
    float inv = 1.f / sum;
    #pragma unroll
    for (int i = 0; i < 9; ++i) sc[i] = e[i] * inv;
  }
  __syncthreads();

  if (t < 64) {
    int h = t >> 3, dg = t & 7;
    float a[8] = {};
    #pragma unroll
    for (int ki = 0; ki < 9; ++ki) {
      float pr = s_sc[h][ki];
      u16x8 vv = *(const u16x8*)&s_kv[ki * 1024 + 512 + h * 64 + dg * 8];
      #pragma unroll
      for (int j = 0; j < 8; ++j) a[j] += pr * bf2f(vv[j]);
    }
    u16x8 o8;
    #pragma unroll
    for (int j = 0; j < 8; ++j) o8[j] = f2bf(a[j]);
    *(u16x8*)&out[(size_t)s * 512 + h * 64 + dg * 8] = o8;
  }
}

// f32 -> bf16 conversion, grid-stride, n % 4 == 0.
__global__ __launch_bounds__(256) void cvt_k(const float* __restrict__ in,
                                             u16* __restrict__ out, long n)
{
  long i = ((long)blockIdx.x * 256 + threadIdx.x) * 4;
  long stride = (long)gridDim.x * 1024;
  for (; i < n; i += stride) {
    float4 f = *(const float4*)&in[i];
    u16x4 o; o.x = f2bf(f.x); o.y = f2bf(f.y); o.z = f2bf(f.z); o.w = f2bf(f.w);
    *(u16x4*)&out[i] = o;
  }
}

// ---------------------------------------------------------------------------
// Host launcher
// ---------------------------------------------------------------------------
extern "C" void kernel_launch(void* const* d_in, const int* in_sizes, int n_in,
                              void* d_out, int out_size, void* d_ws, size_t ws_size,
                              hipStream_t stream)
{
  const float* patches  = (const float*)d_in[0];
  const float* w_pe     = (const float*)d_in[1];
  const float* b_pe     = (const float*)d_in[2];
  const float* pos      = (const float*)d_in[3];
  const float* sa_in_w  = (const float*)d_in[4];
  const float* sa_in_b  = (const float*)d_in[5];
  const float* sa_out_w = (const float*)d_in[6];
  const float* sa_out_b = (const float*)d_in[7];
  const float* g1       = (const float*)d_in[8];
  const float* beta1    = (const float*)d_in[9];
  const float* ca_in_w  = (const float*)d_in[10];
  const float* ca_in_b  = (const float*)d_in[11];
  const float* ca_out_w = (const float*)d_in[12];
  const float* ca_out_b = (const float*)d_in[13];
  const float* g2       = (const float*)d_in[14];
  const float* beta2    = (const float*)d_in[15];
  const float* w1       = (const float*)d_in[16];
  const float* b1       = (const float*)d_in[17];
  const float* w2       = (const float*)d_in[18];
  const float* b2       = (const float*)d_in[19];
  const float* g3       = (const float*)d_in[20];
  const float* beta3    = (const float*)d_in[21];
  float* out = (float*)d_out;

  // workspace layout (bytes)
  char* base = (char*)d_ws;
  u16* wbf        = (u16*)base;
  u16* w_pe_bf    = wbf;
  u16* sa_in_bf   = wbf + 393216;
  u16* sa_out_bf  = wbf + 1179648;
  u16* ca_in_bf   = wbf + 1441792;
  u16* ca_out_bf  = wbf + 2228224;
  u16* w1_bf      = wbf + 2490368;
  u16* w2_bf      = wbf + 3538944;
  u16* x_bf  = (u16*)(base + 9175040ull);     // [73728,512]
  u16* qkv   = (u16*)(base + 84672512ull);    // [73728,1536]; also pat_bf & CA kv
  u16* pat_bf = qkv;                          // [73728,768] aliased (dead after PE)
  u16* sattn = (u16*)(base + 311164928ull);   // [73728,512]
  u16* q_bf  = (u16*)(base + 386662400ull);   // [8192,512]
  u16* cattn = (u16*)(base + 395051008ull);   // [8192,512]
  u16* csum  = (u16*)(base + 403439616ull);   // [8192,512]
  u16* h_bf  = (u16*)(base + 411828224ull);   // [8192,2048]
  u16* osum  = (u16*)(base + 445382656ull);   // [8192,512]

  // conversions to bf16
  cvt_k<<<2048, 256, 0, stream>>>(patches, pat_bf, 56623104L);
  cvt_k<<<384, 256, 0, stream>>>(w_pe, w_pe_bf, 393216L);
  cvt_k<<<768, 256, 0, stream>>>(sa_in_w, sa_in_bf, 786432L);
  cvt_k<<<256, 256, 0, stream>>>(sa_out_w, sa_out_bf, 262144L);
  cvt_k<<<768, 256, 0, stream>>>(ca_in_w, ca_in_bf, 786432L);
  cvt_k<<<256, 256, 0, stream>>>(ca_out_w, ca_out_bf, 262144L);
  cvt_k<<<1024, 256, 0, stream>>>(w1, w1_bf, 1048576L);
  cvt_k<<<1024, 256, 0, stream>>>(w2, w2_bf, 1048576L);

  // 1. patch embed + bias + pos_embed -> x_bf
  gemm8<true, false, false><<<576, 512, 0, stream>>>(
      pat_bf, 768, w_pe_bf, b_pe, pos, nullptr, 0, x_bf, 73728, 512, 768, 2);
  // 2. SA qkv (overwrites pat_bf region -- pat_bf is dead, input is x_bf)
  gemm8<false, false, false><<<1728, 512, 0, stream>>>(
      x_bf, 512, sa_in_bf, sa_in_b, nullptr, nullptr, 0, qkv, 73728, 1536, 512, 6);
  // 3. SA attention
  sa_attn_k<<<8192, 256, 0, stream>>>(qkv, sattn);
  // 4. SA out proj + residual(x) -> x_bf (elementwise in-place)
  gemm8<false, true, false><<<576, 512, 0, stream>>>(
      sattn, 512, sa_out_bf, sa_out_b, nullptr, x_bf, 512, x_bf, 73728, 512, 512, 2);
  // 5. LN1 (in place)
  ln_k<<<73728 / 4, 256, 0, stream>>>(x_bf, g1, beta1, x_bf, nullptr, 73728);
  // 6. CA q from center token (row stride 9*512, offset 4*512)
  gemm_k<false, false><<<256, 256, 0, stream>>>(
      x_bf + 2048, 4608, ca_in_bf, ca_in_b, nullptr, 0, q_bf, 8192, 512, 512, 4);
  // 7. CA kv (wk|wv = ca_in_w rows 512..1535)
  gemm8<false, false, false><<<1152, 512, 0, stream>>>(
      x_bf, 512, ca_in_bf + 262144, ca_in_b + 512, nullptr, nullptr, 0, qkv, 73728, 1024, 512, 4);
  // 8. CA attention
  ca_attn_k<<<8192, 256, 0, stream>>>(q_bf, qkv, cattn);
  // 9. CA out proj + residual(cq) -> csum
  gemm_k<true, false><<<256, 256, 0, stream>>>(
      cattn, 512, ca_out_bf, ca_out_b, x_bf + 2048, 4608, csum, 8192, 512, 512, 4);
  // 10. LN2 (in place) -> c
  ln_k<<<8192 / 4, 256, 0, stream>>>(csum, g2, beta2, csum, nullptr, 8192);
  // 11. FFN1 + exact GELU -> h_bf
  gemm8<false, false, true><<<256, 512, 0, stream>>>(
      csum, 512, w1_bf, b1, nullptr, nullptr, 0, h_bf, 8192, 2048, 512, 8);
  // 12. FFN2 + residual(c) -> osum
  gemm_k<true, false><<<256, 256, 0, stream>>>(
      h_bf, 2048, w2_bf, b2, csum, 512, osum, 8192, 512, 2048, 4);
  // 13. LN3 -> d_out (f32)
  ln_k<<<8192 / 4, 256, 0, stream>>>(osum, g3, beta3, nullptr, out, 8192);
}

// Round 5
// 808.452 us; speedup vs baseline: 1.9210x; 1.9210x over previous
//
#include <hip/hip_runtime.h>

// ---------------------------------------------------------------------------
// NeighborEmbedder on MI355X (gfx950). Round 5: back to 128x128/BK=32/256thr
// (3 blocks/CU). New: depth-2 prefetch pipeline (3 LDS buffers, counted
// vmcnt(4), one barrier per kt) + granule-XOR LDS swizzle (pre-swizzled
// global source, swizzled ds_read).
// ---------------------------------------------------------------------------

typedef unsigned short u16;
typedef u16   u16x8 __attribute__((ext_vector_type(8)));
typedef u16   u16x4 __attribute__((ext_vector_type(4)));
typedef __bf16 bf16x8 __attribute__((ext_vector_type(8)));
typedef float f32x4 __attribute__((ext_vector_type(4)));

static __device__ __forceinline__ u16 f2bf(float f) {
  union { float f; unsigned u; } v; v.f = f;
  unsigned r = v.u + 0x7FFFu + ((v.u >> 16) & 1u);   // RNE
  return (u16)(r >> 16);
}
static __device__ __forceinline__ float bf2f(u16 u) {
  union { unsigned u; float f; } v; v.u = ((unsigned)u) << 16;
  return v.f;
}

// async global->LDS, 16B per lane. LDS dest wave-uniform base + lane*16.
static __device__ __forceinline__ void gld16(const void* g, void* l) {
  __builtin_amdgcn_global_load_lds(
      (__attribute__((address_space(1))) unsigned int*)(size_t)g,
      (__attribute__((address_space(3))) unsigned int*)(unsigned)(size_t)l,
      16, 0, 0);
}

// bijective XCD-chunked swizzle (m204)
static __device__ __forceinline__ int xcd_swz(int bid, int nwg) {
  int q = nwg >> 3, r = nwg & 7;
  int xcd = bid & 7, sub = bid >> 3;
  return (xcd < r ? xcd * (q + 1) : r * (q + 1) + (xcd - r) * q) + sub;
}

#define BAR   __builtin_amdgcn_s_barrier()
#define VM0   asm volatile("s_waitcnt vmcnt(0)" ::: "memory")
#define VM4   asm volatile("s_waitcnt vmcnt(4)" ::: "memory")

// ---------------------------------------------------------------------------
// gemm_k2: out[M,N](bf16) = A[M,K](bf16) @ W[N,K]^T + bias (+pos/+res/gelu)
// 128x128 tile, BK=32, 256 threads = 4 waves (2M x 2N), each wave 64x64 out.
// Depth-2 prefetch: iter kt stages kt+2 into buf (kt+2)%3; vmcnt(4) keeps the
// newest stage in flight, drains the one needed next iter. One barrier per kt.
// LDS swizzle: 16B-granule g at row r stored at g^(r&3); source pre-swizzled,
// ds_read applies the same XOR (rule #21 both-sides involution).
// Requires M%128==0, N%128==0, K%32==0, K>=64.
// ---------------------------------------------------------------------------
template<bool HAS_POS, bool HAS_RES, bool HAS_GELU>
__global__ __launch_bounds__(256, 3) void gemm_k2(
    const u16* __restrict__ A, int lda,
    const u16* __restrict__ W,
    const float* __restrict__ bias,
    const float* __restrict__ pos,
    const u16* res, int res_stride,
    u16* out,
    int M, int N, int K, int nbx)
{
  __shared__ u16 As[3][4096];   // 3 x 128x32 bf16 = 3 x 8 KB
  __shared__ u16 Bs[3][4096];

  const int t    = threadIdx.x;
  const int lane = t & 63, wv = t >> 6;
  const int swz  = xcd_swz(blockIdx.x, gridDim.x);
  const int bm   = (swz / nbx) * 128, bn = (swz % nbx) * 128;
  const int wr   = wv >> 1, wc = wv & 1;

  // staging geometry: lane l covers row (chunk*16 + (l>>2)), 16B granule (l&3),
  // with SOURCE column granule pre-XOR'd by row&3 (LDS stays linear).
  const int srow = lane >> 2;
  const int skk  = (((lane & 3) ^ (srow & 3)) << 3);   // element offset in row
  // ds_read geometry: logical granule lane>>4, XOR'd with row&3 (= lr&3)
  const int lr = lane & 15;
  const int rg = ((lane >> 4) ^ (lr & 3)) << 3;        // swizzled element off

  f32x4 acc[4][4] = {};

  auto stage = [&](int buf, int kt) {   // 4 gld16 per wave
    #pragma unroll
    for (int c = 0; c < 2; ++c) {
      int rr = (wv + 4 * c) * 16 + srow;
      gld16(A + (size_t)(bm + rr) * lda + kt * 32 + skk, &As[buf][(wv + 4 * c) * 512]);
      gld16(W + (size_t)(bn + rr) * K   + kt * 32 + skk, &Bs[buf][(wv + 4 * c) * 512]);
    }
  };

  const int nkt = K >> 5;
  // prologue: stage kt0 -> buf0, kt1 -> buf1; wait buf0 only
  stage(0, 0);
  stage(1, 1);
  VM4; BAR;

  int cur = 0, st = 2;
  for (int kt = 0; kt < nkt; ++kt) {
    if (kt + 2 < nkt) stage(st, kt + 2);

    bf16x8 a[4], b[4];
    #pragma unroll
    for (int m = 0; m < 4; ++m) {
      int row = wr * 64 + m * 16 + lr;
      a[m] = *(const bf16x8*)&As[cur][row * 32 + rg];
    }
    #pragma unroll
    for (int n = 0; n < 4; ++n) {
      int row = wc * 64 + n * 16 + lr;
      b[n] = *(const bf16x8*)&Bs[cur][row * 32 + rg];
    }
    #pragma unroll
    for (int m = 0; m < 4; ++m)
      #pragma unroll
      for (int n = 0; n < 4; ++n)
        acc[m][n] = __builtin_amdgcn_mfma_f32_16x16x32_bf16(a[m], b[n], acc[m][n], 0, 0, 0);

    if (kt + 2 < nkt) { VM4; } else { VM0; }
    BAR;
    cur = (cur == 2) ? 0 : cur + 1;
    st  = (st  == 2) ? 0 : st  + 1;
  }

  // epilogue: row=(lane>>4)*4+r (+m*16), col=lane&15 (+n*16)  [m89 layout]
  const int lq = lane >> 4;
  #pragma unroll
  for (int m = 0; m < 4; ++m) {
    #pragma unroll
    for (int n = 0; n < 4; ++n) {
      int col = bn + wc * 64 + n * 16 + lr;
      float bv = bias[col];
      #pragma unroll
      for (int r = 0; r < 4; ++r) {
        int row = bm + wr * 64 + m * 16 + lq * 4 + r;
        float v = acc[m][n][r] + bv;
        if constexpr (HAS_POS) v += pos[(row % 9) * 512 + col];
        if constexpr (HAS_RES) v += bf2f(res[(size_t)row * res_stride + col]);
        if constexpr (HAS_GELU) v = 0.5f * v * (1.f + erff(v * 0.70710678118f));
        out[(size_t)row * N + col] = f2bf(v);
      }
    }
  }
}

// ---------------------------------------------------------------------------
// LayerNorm over rows of 512 (bf16 in). One wave per row, 4 rows per block.
// ---------------------------------------------------------------------------
__global__ __launch_bounds__(256) void ln_k(
    const u16* in,
    const float* __restrict__ g, const float* __restrict__ be,
    u16* out_bf, float* out_f32, int rows)
{
  int wv = threadIdx.x >> 6, lane = threadIdx.x & 63;
  int row = blockIdx.x * 4 + wv;
  if (row >= rows) return;
  const u16* p = in + (size_t)row * 512;
  u16x8 v = *(const u16x8*)&p[lane * 8];
  float x[8], s = 0.f, sq = 0.f;
  #pragma unroll
  for (int j = 0; j < 8; ++j) { x[j] = bf2f(v[j]); s += x[j]; sq += x[j] * x[j]; }
  #pragma unroll
  for (int o = 32; o > 0; o >>= 1) { s += __shfl_xor(s, o, 64); sq += __shfl_xor(sq, o, 64); }
  float mean = s * (1.f / 512.f);
  float var  = sq * (1.f / 512.f) - mean * mean;
  float rs   = rsqrtf(var + 1e-5f);
  float y[8];
  #pragma unroll
  for (int j = 0; j < 8; ++j) {
    int c = lane * 8 + j;
    y[j] = (x[j] - mean) * rs * g[c] + be[c];
  }
  if (out_bf) {
    u16x8 o8;
    #pragma unroll
    for (int j = 0; j < 8; ++j) o8[j] = f2bf(y[j]);
    *(u16x8*)&out_bf[(size_t)row * 512 + lane * 8] = o8;
  }
  if (out_f32) {
    #pragma unroll
    for (int j = 0; j < 8; ++j) out_f32[(size_t)row * 512 + lane * 8 + j] = y[j];
  }
}

// ---------------------------------------------------------------------------
// Self-attention, one block per sample: qkv[9,1536] (q|k|v), H=8, d=64, L=9.
// ---------------------------------------------------------------------------
__global__ __launch_bounds__(256) void sa_attn_k(const u16* __restrict__ qkv,
                                                 u16* __restrict__ out)
{
  __shared__ u16  s_qkv[9 * 1536];
  __shared__ float s_sc[8][81];
  const int s = blockIdx.x, t = threadIdx.x;
  const u16* src = qkv + (size_t)s * 9 * 1536;
  for (int i = t; i < (9 * 1536) / 8; i += 256)
    *(u16x8*)&s_qkv[i * 8] = *(const u16x8*)&src[i * 8];
  __syncthreads();

  const int h = t >> 5, sl = t & 31;
  for (int p = sl; p < 81; p += 32) {
    int qi = p / 9, ki = p % 9;
    const u16* qp = &s_qkv[qi * 1536 + h * 64];
    const u16* kp = &s_qkv[ki * 1536 + 512 + h * 64];
    float d = 0.f;
    #pragma unroll
    for (int e8 = 0; e8 < 8; ++e8) {
      u16x8 qv = *(const u16x8*)&qp[e8 * 8];
      u16x8 kv = *(const u16x8*)&kp[e8 * 8];
      #pragma unroll
      for (int j = 0; j < 8; ++j) d += bf2f(qv[j]) * bf2f(kv[j]);
    }
    s_sc[h][p] = d * 0.125f;
  }
  __syncthreads();

  if (t < 72) {
    int hh = t / 9, qi = t % 9;
    float* sc = &s_sc[hh][qi * 9];
    float mx = sc[0];
    #pragma unroll
    for (int i = 1; i < 9; ++i) mx = fmaxf(mx, sc[i]);
    float e[9], sum = 0.f;
    #pragma unroll
    for (int i = 0; i < 9; ++i) { e[i] = __expf(sc[i] - mx); sum += e[i]; }
    float inv = 1.f / sum;
    #pragma unroll
    for (int i = 0; i < 9; ++i) sc[i] = e[i] * inv;
  }
  __syncthreads();

  for (int gidx = sl; gidx < 72; gidx += 32) {
    int qi = gidx >> 3, dg = gidx & 7;
    float a[8] = {};
    #pragma unroll
    for (int ki = 0; ki < 9; ++ki) {
      float pr = s_sc[h][qi * 9 + ki];
      u16x8 vv = *(const u16x8*)&s_qkv[ki * 1536 + 1024 + h * 64 + dg * 8];
      #pragma unroll
      for (int j = 0; j < 8; ++j) a[j] += pr * bf2f(vv[j]);
    }
    u16x8 o8;
    #pragma unroll
    for (int j = 0; j < 8; ++j) o8[j] = f2bf(a[j]);
    *(u16x8*)&out[((size_t)s * 9 + qi) * 512 + h * 64 + dg * 8] = o8;
  }
}

// ---------------------------------------------------------------------------
// Cross-attention, one block per sample: q[512], kv[9,1024] (k|v).
// ---------------------------------------------------------------------------
__global__ __launch_bounds__(256) void ca_attn_k(const u16* __restrict__ q,
                                                 const u16* __restrict__ kv,
                                                 u16* __restrict__ out)
{
  __shared__ u16  s_q[512];
  __shared__ u16  s_kv[9 * 1024];
  __shared__ float s_sc[8][9];
  const int s = blockIdx.x, t = threadIdx.x;
  if (t < 64) *(u16x8*)&s_q[t * 8] = *(const u16x8*)&q[(size_t)s * 512 + t * 8];
  for (int i = t; i < (9 * 1024) / 8; i += 256)
    *(u16x8*)&s_kv[i * 8] = *(const u16x8*)&kv[(size_t)s * 9 * 1024 + i * 8];
  __syncthreads();

  if (t < 72) {
    int h = t / 9, ki = t % 9;
    const u16* qp = &s_q[h * 64];
    const u16* kp = &s_kv[ki * 1024 + h * 64];
    float d = 0.f;
    #pragma unroll
    for (int e8 = 0; e8 < 8; ++e8) {
      u16x8 qv = *(const u16x8*)&qp[e8 * 8];
      u16x8 kvv = *(const u16x8*)&kp[e8 * 8];
      #pragma unroll
      for (int j = 0; j < 8; ++j) d += bf2f(qv[j]) * bf2f(kvv[j]);
    }
    s_sc[h][ki] = d * 0.125f;
  }
  __syncthreads();

  if (t < 8) {
    float* sc = s_sc[t];
    float mx = sc[0];
    #pragma unroll
    for (int i = 1; i < 9; ++i) mx = fmaxf(mx, sc[i]);
    float e[9], sum = 0.f;
    #pragma unroll
    for (int i = 0; i < 9; ++i) { e[i] = __expf(sc[i] - mx); sum += e[i]; }
    float inv = 1.f / sum;
    #pragma unroll
    for (int i = 0; i < 9; ++i) sc[i] = e[i] * inv;
  }
  __syncthreads();

  if (t < 64) {
    int h = t >> 3, dg = t & 7;
    float a[8] = {};
    #pragma unroll
    for (int ki = 0; ki < 9; ++ki) {
      float pr = s_sc[h][ki];
      u16x8 vv = *(const u16x8*)&s_kv[ki * 1024 + 512 + h * 64 + dg * 8];
      #pragma unroll
      for (int j = 0; j < 8; ++j) a[j] += pr * bf2f(vv[j]);
    }
    u16x8 o8;
    #pragma unroll
    for (int j = 0; j < 8; ++j) o8[j] = f2bf(a[j]);
    *(u16x8*)&out[(size_t)s * 512 + h * 64 + dg * 8] = o8;
  }
}

// f32 -> bf16 conversion, grid-stride, n % 4 == 0.
__global__ __launch_bounds__(256) void cvt_k(const float* __restrict__ in,
                                             u16* __restrict__ out, long n)
{
  long i = ((long)blockIdx.x * 256 + threadIdx.x) * 4;
  long stride = (long)gridDim.x * 1024;
  for (; i < n; i += stride) {
    float4 f = *(const float4*)&in[i];
    u16x4 o; o.x = f2bf(f.x); o.y = f2bf(f.y); o.z = f2bf(f.z); o.w = f2bf(f.w);
    *(u16x4*)&out[i] = o;
  }
}

// ---------------------------------------------------------------------------
// Host launcher
// ---------------------------------------------------------------------------
extern "C" void kernel_launch(void* const* d_in, const int* in_sizes, int n_in,
                              void* d_out, int out_size, void* d_ws, size_t ws_size,
                              hipStream_t stream)
{
  const float* patches  = (const float*)d_in[0];
  const float* w_pe     = (const float*)d_in[1];
  const float* b_pe     = (const float*)d_in[2];
  const float* pos      = (const float*)d_in[3];
  const float* sa_in_w  = (const float*)d_in[4];
  const float* sa_in_b  = (const float*)d_in[5];
  const float* sa_out_w = (const float*)d_in[6];
  const float* sa_out_b = (const float*)d_in[7];
  const float* g1       = (const float*)d_in[8];
  const float* beta1    = (const float*)d_in[9];
  const float* ca_in_w  = (const float*)d_in[10];
  const float* ca_in_b  = (const float*)d_in[11];
  const float* ca_out_w = (const float*)d_in[12];
  const float* ca_out_b = (const float*)d_in[13];
  const float* g2       = (const float*)d_in[14];
  const float* beta2    = (const float*)d_in[15];
  const float* w1       = (const float*)d_in[16];
  const float* b1       = (const float*)d_in[17];
  const float* w2       = (const float*)d_in[18];
  const float* b2       = (const float*)d_in[19];
  const float* g3       = (const float*)d_in[20];
  const float* beta3    = (const float*)d_in[21];
  float* out = (float*)d_out;

  // workspace layout (bytes)
  char* base = (char*)d_ws;
  u16* wbf        = (u16*)base;
  u16* w_pe_bf    = wbf;
  u16* sa_in_bf   = wbf + 393216;
  u16* sa_out_bf  = wbf + 1179648;
  u16* ca_in_bf   = wbf + 1441792;
  u16* ca_out_bf  = wbf + 2228224;
  u16* w1_bf      = wbf + 2490368;
  u16* w2_bf      = wbf + 3538944;
  u16* x_bf  = (u16*)(base + 9175040ull);     // [73728,512]
  u16* qkv   = (u16*)(base + 84672512ull);    // [73728,1536]; also pat_bf & CA kv
  u16* pat_bf = qkv;                          // [73728,768] aliased (dead after PE)
  u16* sattn = (u16*)(base + 311164928ull);   // [73728,512]
  u16* q_bf  = (u16*)(base + 386662400ull);   // [8192,512]
  u16* cattn = (u16*)(base + 395051008ull);   // [8192,512]
  u16* csum  = (u16*)(base + 403439616ull);   // [8192,512]
  u16* h_bf  = (u16*)(base + 411828224ull);   // [8192,2048]
  u16* osum  = (u16*)(base + 445382656ull);   // [8192,512]

  // conversions to bf16
  cvt_k<<<2048, 256, 0, stream>>>(patches, pat_bf, 56623104L);
  cvt_k<<<384, 256, 0, stream>>>(w_pe, w_pe_bf, 393216L);
  cvt_k<<<768, 256, 0, stream>>>(sa_in_w, sa_in_bf, 786432L);
  cvt_k<<<256, 256, 0, stream>>>(sa_out_w, sa_out_bf, 262144L);
  cvt_k<<<768, 256, 0, stream>>>(ca_in_w, ca_in_bf, 786432L);
  cvt_k<<<256, 256, 0, stream>>>(ca_out_w, ca_out_bf, 262144L);
  cvt_k<<<1024, 256, 0, stream>>>(w1, w1_bf, 1048576L);
  cvt_k<<<1024, 256, 0, stream>>>(w2, w2_bf, 1048576L);

  // 1. patch embed + bias + pos_embed -> x_bf
  gemm_k2<true, false, false><<<2304, 256, 0, stream>>>(
      pat_bf, 768, w_pe_bf, b_pe, pos, nullptr, 0, x_bf, 73728, 512, 768, 4);
  // 2. SA qkv (overwrites pat_bf region -- pat_bf dead, input is x_bf)
  gemm_k2<false, false, false><<<6912, 256, 0, stream>>>(
      x_bf, 512, sa_in_bf, sa_in_b, nullptr, nullptr, 0, qkv, 73728, 1536, 512, 12);
  // 3. SA attention
  sa_attn_k<<<8192, 256, 0, stream>>>(qkv, sattn);
  // 4. SA out proj + residual(x) -> x_bf (elementwise in-place)
  gemm_k2<false, true, false><<<2304, 256, 0, stream>>>(
      sattn, 512, sa_out_bf, sa_out_b, nullptr, x_bf, 512, x_bf, 73728, 512, 512, 4);
  // 5. LN1 (in place)
  ln_k<<<73728 / 4, 256, 0, stream>>>(x_bf, g1, beta1, x_bf, nullptr, 73728);
  // 6. CA q from center token (row stride 9*512, offset 4*512)
  gemm_k2<false, false, false><<<256, 256, 0, stream>>>(
      x_bf + 2048, 4608, ca_in_bf, ca_in_b, nullptr, nullptr, 0, q_bf, 8192, 512, 512, 4);
  // 7. CA kv (wk|wv = ca_in_w rows 512..1535)
  gemm_k2<false, false, false><<<4608, 256, 0, stream>>>(
      x_bf, 512, ca_in_bf + 262144, ca_in_b + 512, nullptr, nullptr, 0, qkv, 73728, 1024, 512, 8);
  // 8. CA attention
  ca_attn_k<<<8192, 256, 0, stream>>>(q_bf, qkv, cattn);
  // 9. CA out proj + residual(cq) -> csum
  gemm_k2<false, true, false><<<256, 256, 0, stream>>>(
      cattn, 512, ca_out_bf, ca_out_b, nullptr, x_bf + 2048, 4608, csum, 8192, 512, 512, 4);
  // 10. LN2 (in place) -> c
  ln_k<<<8192 / 4, 256, 0, stream>>>(csum, g2, beta2, csum, nullptr, 8192);
  // 11. FFN1 + exact GELU -> h_bf
  gemm_k2<false, false, true><<<1024, 256, 0, stream>>>(
      csum, 512, w1_bf, b1, nullptr, nullptr, 0, h_bf, 8192, 2048, 512, 16);
  // 12. FFN2 + residual(c) -> osum
  gemm_k2<false, true, false><<<256, 256, 0, stream>>>(
      h_bf, 2048, w2_bf, b2, nullptr, csum, 512, osum, 8192, 512, 2048, 4);
  // 13. LN3 -> d_out (f32)
  ln_k<<<8192 / 4, 256, 0, stream>>>(osum, g3, beta3, nullptr, out, 8192);
}

// Round 6
// 805.857 us; speedup vs baseline: 1.9272x; 1.0032x over previous
//
#include <hip/hip_runtime.h>

// ---------------------------------------------------------------------------
// NeighborEmbedder on MI355X (gfx950). Round 6: fix the LDS swizzle row bits.
// Bank_start = (row&1)*16 + g*4 (8 slots); XOR granule with (row>>1)&3 so the
// 16 rows per quarter-wave map 2-to-1 onto slots (2-way = free, m136).
// Structure unchanged from R5: 128x128/BK=32/256thr, 3-buffer depth-2
// prefetch, counted vmcnt(4), XCD-chunked block swizzle.
// ---------------------------------------------------------------------------

typedef unsigned short u16;
typedef u16   u16x8 __attribute__((ext_vector_type(8)));
typedef u16   u16x4 __attribute__((ext_vector_type(4)));
typedef __bf16 bf16x8 __attribute__((ext_vector_type(8)));
typedef float f32x4 __attribute__((ext_vector_type(4)));

static __device__ __forceinline__ u16 f2bf(float f) {
  union { float f; unsigned u; } v; v.f = f;
  unsigned r = v.u + 0x7FFFu + ((v.u >> 16) & 1u);   // RNE
  return (u16)(r >> 16);
}
static __device__ __forceinline__ float bf2f(u16 u) {
  union { unsigned u; float f; } v; v.u = ((unsigned)u) << 16;
  return v.f;
}

// async global->LDS, 16B per lane. LDS dest wave-uniform base + lane*16.
static __device__ __forceinline__ void gld16(const void* g, void* l) {
  __builtin_amdgcn_global_load_lds(
      (__attribute__((address_space(1))) unsigned int*)(size_t)g,
      (__attribute__((address_space(3))) unsigned int*)(unsigned)(size_t)l,
      16, 0, 0);
}

// bijective XCD-chunked swizzle (m204)
static __device__ __forceinline__ int xcd_swz(int bid, int nwg) {
  int q = nwg >> 3, r = nwg & 7;
  int xcd = bid & 7, sub = bid >> 3;
  return (xcd < r ? xcd * (q + 1) : r * (q + 1) + (xcd - r) * q) + sub;
}

#define BAR   __builtin_amdgcn_s_barrier()
#define VM0   asm volatile("s_waitcnt vmcnt(0)" ::: "memory")
#define VM4   asm volatile("s_waitcnt vmcnt(4)" ::: "memory")

// ---------------------------------------------------------------------------
// gemm_k2: out[M,N](bf16) = A[M,K](bf16) @ W[N,K]^T + bias (+pos/+res/gelu)
// 128x128 tile, BK=32, 256 threads = 4 waves (2M x 2N), each wave 64x64 out.
// Depth-2 prefetch: iter kt stages kt+2 into buf (kt+2)%3; vmcnt(4) keeps the
// newest stage in flight, drains the one needed next iter. One barrier per kt.
// LDS swizzle: 16B-granule g at row r stored at g ^ ((r>>1)&3); source
// pre-swizzled, ds_read applies the same XOR (both-sides involution).
// Requires M%128==0, N%128==0, K%32==0, K>=64.
// ---------------------------------------------------------------------------
template<bool HAS_POS, bool HAS_RES, bool HAS_GELU>
__global__ __launch_bounds__(256, 3) void gemm_k2(
    const u16* __restrict__ A, int lda,
    const u16* __restrict__ W,
    const float* __restrict__ bias,
    const float* __restrict__ pos,
    const u16* res, int res_stride,
    u16* out,
    int M, int N, int K, int nbx)
{
  __shared__ u16 As[3][4096];   // 3 x 128x32 bf16 = 3 x 8 KB
  __shared__ u16 Bs[3][4096];

  const int t    = threadIdx.x;
  const int lane = t & 63, wv = t >> 6;
  const int swz  = xcd_swz(blockIdx.x, gridDim.x);
  const int bm   = (swz / nbx) * 128, bn = (swz % nbx) * 128;
  const int wr   = wv >> 1, wc = wv & 1;

  // staging geometry: lane l covers row (chunk*16 + (l>>2)), 16B granule l&3.
  // SOURCE granule pre-XOR'd with (row>>1)&3 = (l>>3)&3 (LDS stays linear).
  const int srow = lane >> 2;
  const int skk  = (((lane & 3) ^ ((lane >> 3) & 3)) << 3);  // elem offset
  // ds_read geometry: logical granule lane>>4 XOR'd with (row>>1)&3 = (lr>>1)&3
  const int lr = lane & 15;
  const int rg = (((lane >> 4) ^ ((lr >> 1) & 3)) << 3);     // swizzled elems

  f32x4 acc[4][4] = {};

  auto stage = [&](int buf, int kt) {   // 4 gld16 per wave
    #pragma unroll
    for (int c = 0; c < 2; ++c) {
      int rr = (wv + 4 * c) * 16 + srow;
      gld16(A + (size_t)(bm + rr) * lda + kt * 32 + skk, &As[buf][(wv + 4 * c) * 512]);
      gld16(W + (size_t)(bn + rr) * K   + kt * 32 + skk, &Bs[buf][(wv + 4 * c) * 512]);
    }
  };

  const int nkt = K >> 5;
  // prologue: stage kt0 -> buf0, kt1 -> buf1; wait buf0 only
  stage(0, 0);
  stage(1, 1);
  VM4; BAR;

  int cur = 0, st = 2;
  for (int kt = 0; kt < nkt; ++kt) {
    if (kt + 2 < nkt) stage(st, kt + 2);

    bf16x8 a[4], b[4];
    #pragma unroll
    for (int m = 0; m < 4; ++m) {
      int row = wr * 64 + m * 16 + lr;
      a[m] = *(const bf16x8*)&As[cur][row * 32 + rg];
    }
    #pragma unroll
    for (int n = 0; n < 4; ++n) {
      int row = wc * 64 + n * 16 + lr;
      b[n] = *(const bf16x8*)&Bs[cur][row * 32 + rg];
    }
    #pragma unroll
    for (int m = 0; m < 4; ++m)
      #pragma unroll
      for (int n = 0; n < 4; ++n)
        acc[m][n] = __builtin_amdgcn_mfma_f32_16x16x32_bf16(a[m], b[n], acc[m][n], 0, 0, 0);

    if (kt + 2 < nkt) { VM4; } else { VM0; }
    BAR;
    cur = (cur == 2) ? 0 : cur + 1;
    st  = (st  == 2) ? 0 : st  + 1;
  }

  // epilogue: row=(lane>>4)*4+r (+m*16), col=lane&15 (+n*16)  [m89 layout]
  const int lq = lane >> 4;
  #pragma unroll
  for (int m = 0; m < 4; ++m) {
    #pragma unroll
    for (int n = 0; n < 4; ++n) {
      int col = bn + wc * 64 + n * 16 + lr;
      float bv = bias[col];
      #pragma unroll
      for (int r = 0; r < 4; ++r) {
        int row = bm + wr * 64 + m * 16 + lq * 4 + r;
        float v = acc[m][n][r] + bv;
        if constexpr (HAS_POS) v += pos[(row % 9) * 512 + col];
        if constexpr (HAS_RES) v += bf2f(res[(size_t)row * res_stride + col]);
        if constexpr (HAS_GELU) v = 0.5f * v * (1.f + erff(v * 0.70710678118f));
        out[(size_t)row * N + col] = f2bf(v);
      }
    }
  }
}

// ---------------------------------------------------------------------------
// LayerNorm over rows of 512 (bf16 in). One wave per row, 4 rows per block.
// ---------------------------------------------------------------------------
__global__ __launch_bounds__(256) void ln_k(
    const u16* in,
    const float* __restrict__ g, const float* __restrict__ be,
    u16* out_bf, float* out_f32, int rows)
{
  int wv = threadIdx.x >> 6, lane = threadIdx.x & 63;
  int row = blockIdx.x * 4 + wv;
  if (row >= rows) return;
  const u16* p = in + (size_t)row * 512;
  u16x8 v = *(const u16x8*)&p[lane * 8];
  float x[8], s = 0.f, sq = 0.f;
  #pragma unroll
  for (int j = 0; j < 8; ++j) { x[j] = bf2f(v[j]); s += x[j]; sq += x[j] * x[j]; }
  #pragma unroll
  for (int o = 32; o > 0; o >>= 1) { s += __shfl_xor(s, o, 64); sq += __shfl_xor(sq, o, 64); }
  float mean = s * (1.f / 512.f);
  float var  = sq * (1.f / 512.f) - mean * mean;
  float rs   = rsqrtf(var + 1e-5f);
  float y[8];
  #pragma unroll
  for (int j = 0; j < 8; ++j) {
    int c = lane * 8 + j;
    y[j] = (x[j] - mean) * rs * g[c] + be[c];
  }
  if (out_bf) {
    u16x8 o8;
    #pragma unroll
    for (int j = 0; j < 8; ++j) o8[j] = f2bf(y[j]);
    *(u16x8*)&out_bf[(size_t)row * 512 + lane * 8] = o8;
  }
  if (out_f32) {
    #pragma unroll
    for (int j = 0; j < 8; ++j) out_f32[(size_t)row * 512 + lane * 8 + j] = y[j];
  }
}

// ---------------------------------------------------------------------------
// Self-attention, one block per sample: qkv[9,1536] (q|k|v), H=8, d=64, L=9.
// ---------------------------------------------------------------------------
__global__ __launch_bounds__(256) void sa_attn_k(const u16* __restrict__ qkv,
                                                 u16* __restrict__ out)
{
  __shared__ u16  s_qkv[9 * 1536];
  __shared__ float s_sc[8][81];
  const int s = blockIdx.x, t = threadIdx.x;
  const u16* src = qkv + (size_t)s * 9 * 1536;
  for (int i = t; i < (9 * 1536) / 8; i += 256)
    *(u16x8*)&s_qkv[i * 8] = *(const u16x8*)&src[i * 8];
  __syncthreads();

  const int h = t >> 5, sl = t & 31;
  for (int p = sl; p < 81; p += 32) {
    int qi = p / 9, ki = p % 9;
    const u16* qp = &s_qkv[qi * 1536 + h * 64];
    const u16* kp = &s_qkv[ki * 1536 + 512 + h * 64];
    float d = 0.f;
    #pragma unroll
    for (int e8 = 0; e8 < 8; ++e8) {
      u16x8 qv = *(const u16x8*)&qp[e8 * 8];
      u16x8 kv = *(const u16x8*)&kp[e8 * 8];
      #pragma unroll
      for (int j = 0; j < 8; ++j) d += bf2f(qv[j]) * bf2f(kv[j]);
    }
    s_sc[h][p] = d * 0.125f;
  }
  __syncthreads();

  if (t < 72) {
    int hh = t / 9, qi = t % 9;
    float* sc = &s_sc[hh][qi * 9];
    float mx = sc[0];
    #pragma unroll
    for (int i = 1; i < 9; ++i) mx = fmaxf(mx, sc[i]);
    float e[9], sum = 0.f;
    #pragma unroll
    for (int i = 0; i < 9; ++i) { e[i] = __expf(sc[i] - mx); sum += e[i]; }
    float inv = 1.f / sum;
    #pragma unroll
    for (int i = 0; i < 9; ++i) sc[i] = e[i] * inv;
  }
  __syncthreads();

  for (int gidx = sl; gidx < 72; gidx += 32) {
    int qi = gidx >> 3, dg = gidx & 7;
    float a[8] = {};
    #pragma unroll
    for (int ki = 0; ki < 9; ++ki) {
      float pr = s_sc[h][qi * 9 + ki];
      u16x8 vv = *(const u16x8*)&s_qkv[ki * 1536 + 1024 + h * 64 + dg * 8];
      #pragma unroll
      for (int j = 0; j < 8; ++j) a[j] += pr * bf2f(vv[j]);
    }
    u16x8 o8;
    #pragma unroll
    for (int j = 0; j < 8; ++j) o8[j] = f2bf(a[j]);
    *(u16x8*)&out[((size_t)s * 9 + qi) * 512 + h * 64 + dg * 8] = o8;
  }
}

// ---------------------------------------------------------------------------
// Cross-attention, one block per sample: q[512], kv[9,1024] (k|v).
// ---------------------------------------------------------------------------
__global__ __launch_bounds__(256) void ca_attn_k(const u16* __restrict__ q,
                                                 const u16* __restrict__ kv,
                                                 u16* __restrict__ out)
{
  __shared__ u16  s_q[512];
  __shared__ u16  s_kv[9 * 1024];
  __shared__ float s_sc[8][9];
  const int s = blockIdx.x, t = threadIdx.x;
  if (t < 64) *(u16x8*)&s_q[t * 8] = *(const u16x8*)&q[(size_t)s * 512 + t * 8];
  for (int i = t; i < (9 * 1024) / 8; i += 256)
    *(u16x8*)&s_kv[i * 8] = *(const u16x8*)&kv[(size_t)s * 9 * 1024 + i * 8];
  __syncthreads();

  if (t < 72) {
    int h = t / 9, ki = t % 9;
    const u16* qp = &s_q[h * 64];
    const u16* kp = &s_kv[ki * 1024 + h * 64];
    float d = 0.f;
    #pragma unroll
    for (int e8 = 0; e8 < 8; ++e8) {
      u16x8 qv = *(const u16x8*)&qp[e8 * 8];
      u16x8 kvv = *(const u16x8*)&kp[e8 * 8];
      #pragma unroll
      for (int j = 0; j < 8; ++j) d += bf2f(qv[j]) * bf2f(kvv[j]);
    }
    s_sc[h][ki] = d * 0.125f;
  }
  __syncthreads();

  if (t < 8) {
    float* sc = s_sc[t];
    float mx = sc[0];
    #pragma unroll
    for (int i = 1; i < 9; ++i) mx = fmaxf(mx, sc[i]);
    float e[9], sum = 0.f;
    #pragma unroll
    for (int i = 0; i < 9; ++i) { e[i] = __expf(sc[i] - mx); sum += e[i]; }
    float inv = 1.f / sum;
    #pragma unroll
    for (int i = 0; i < 9; ++i) sc[i] = e[i] * inv;
  }
  __syncthreads();

  if (t < 64) {
    int h = t >> 3, dg = t & 7;
    float a[8] = {};
    #pragma unroll
    for (int ki = 0; ki < 9; ++ki) {
      float pr = s_sc[h][ki];
      u16x8 vv = *(const u16x8*)&s_kv[ki * 1024 + 512 + h * 64 + dg * 8];
      #pragma unroll
      for (int j = 0; j < 8; ++j) a[j] += pr * bf2f(vv[j]);
    }
    u16x8 o8;
    #pragma unroll
    for (int j = 0; j < 8; ++j) o8[j] = f2bf(a[j]);
    *(u16x8*)&out[(size_t)s * 512 + h * 64 + dg * 8] = o8;
  }
}

// f32 -> bf16 conversion, grid-stride, n % 4 == 0.
__global__ __launch_bounds__(256) void cvt_k(const float* __restrict__ in,
                                             u16* __restrict__ out, long n)
{
  long i = ((long)blockIdx.x * 256 + threadIdx.x) * 4;
  long stride = (long)gridDim.x * 1024;
  for (; i < n; i += stride) {
    float4 f = *(const float4*)&in[i];
    u16x4 o; o.x = f2bf(f.x); o.y = f2bf(f.y); o.z = f2bf(f.z); o.w = f2bf(f.w);
    *(u16x4*)&out[i] = o;
  }
}

// ---------------------------------------------------------------------------
// Host launcher
// ---------------------------------------------------------------------------
extern "C" void kernel_launch(void* const* d_in, const int* in_sizes, int n_in,
                              void* d_out, int out_size, void* d_ws, size_t ws_size,
                              hipStream_t stream)
{
  const float* patches  = (const float*)d_in[0];
  const float* w_pe     = (const float*)d_in[1];
  const float* b_pe     = (const float*)d_in[2];
  const float* pos      = (const float*)d_in[3];
  const float* sa_in_w  = (const float*)d_in[4];
  const float* sa_in_b  = (const float*)d_in[5];
  const float* sa_out_w = (const float*)d_in[6];
  const float* sa_out_b = (const float*)d_in[7];
  const float* g1       = (const float*)d_in[8];
  const float* beta1    = (const float*)d_in[9];
  const float* ca_in_w  = (const float*)d_in[10];
  const float* ca_in_b  = (const float*)d_in[11];
  const float* ca_out_w = (const float*)d_in[12];
  const float* ca_out_b = (const float*)d_in[13];
  const float* g2       = (const float*)d_in[14];
  const float* beta2    = (const float*)d_in[15];
  const float* w1       = (const float*)d_in[16];
  const float* b1       = (const float*)d_in[17];
  const float* w2       = (const float*)d_in[18];
  const float* b2       = (const float*)d_in[19];
  const float* g3       = (const float*)d_in[20];
  const float* beta3    = (const float*)d_in[21];
  float* out = (float*)d_out;

  // workspace layout (bytes)
  char* base = (char*)d_ws;
  u16* wbf        = (u16*)base;
  u16* w_pe_bf    = wbf;
  u16* sa_in_bf   = wbf + 393216;
  u16* sa_out_bf  = wbf + 1179648;
  u16* ca_in_bf   = wbf + 1441792;
  u16* ca_out_bf  = wbf + 2228224;
  u16* w1_bf      = wbf + 2490368;
  u16* w2_bf      = wbf + 3538944;
  u16* x_bf  = (u16*)(base + 9175040ull);     // [73728,512]
  u16* qkv   = (u16*)(base + 84672512ull);    // [73728,1536]; also pat_bf & CA kv
  u16* pat_bf = qkv;                          // [73728,768] aliased (dead after PE)
  u16* sattn = (u16*)(base + 311164928ull);   // [73728,512]
  u16* q_bf  = (u16*)(base + 386662400ull);   // [8192,512]
  u16* cattn = (u16*)(base + 395051008ull);   // [8192,512]
  u16* csum  = (u16*)(base + 403439616ull);   // [8192,512]
  u16* h_bf  = (u16*)(base + 411828224ull);   // [8192,2048]
  u16* osum  = (u16*)(base + 445382656ull);   // [8192,512]

  // conversions to bf16
  cvt_k<<<2048, 256, 0, stream>>>(patches, pat_bf, 56623104L);
  cvt_k<<<384, 256, 0, stream>>>(w_pe, w_pe_bf, 393216L);
  cvt_k<<<768, 256, 0, stream>>>(sa_in_w, sa_in_bf, 786432L);
  cvt_k<<<256, 256, 0, stream>>>(sa_out_w, sa_out_bf, 262144L);
  cvt_k<<<768, 256, 0, stream>>>(ca_in_w, ca_in_bf, 786432L);
  cvt_k<<<256, 256, 0, stream>>>(ca_out_w, ca_out_bf, 262144L);
  cvt_k<<<1024, 256, 0, stream>>>(w1, w1_bf, 1048576L);
  cvt_k<<<1024, 256, 0, stream>>>(w2, w2_bf, 1048576L);

  // 1. patch embed + bias + pos_embed -> x_bf
  gemm_k2<true, false, false><<<2304, 256, 0, stream>>>(
      pat_bf, 768, w_pe_bf, b_pe, pos, nullptr, 0, x_bf, 73728, 512, 768, 4);
  // 2. SA qkv (overwrites pat_bf region -- pat_bf dead, input is x_bf)
  gemm_k2<false, false, false><<<6912, 256, 0, stream>>>(
      x_bf, 512, sa_in_bf, sa_in_b, nullptr, nullptr, 0, qkv, 73728, 1536, 512, 12);
  // 3. SA attention
  sa_attn_k<<<8192, 256, 0, stream>>>(qkv, sattn);
  // 4. SA out proj + residual(x) -> x_bf (elementwise in-place)
  gemm_k2<false, true, false><<<2304, 256, 0, stream>>>(
      sattn, 512, sa_out_bf, sa_out_b, nullptr, x_bf, 512, x_bf, 73728, 512, 512, 4);
  // 5. LN1 (in place)
  ln_k<<<73728 / 4, 256, 0, stream>>>(x_bf, g1, beta1, x_bf, nullptr, 73728);
  // 6. CA q from center token (row stride 9*512, offset 4*512)
  gemm_k2<false, false, false><<<256, 256, 0, stream>>>(
      x_bf + 2048, 4608, ca_in_bf, ca_in_b, nullptr, nullptr, 0, q_bf, 8192, 512, 512, 4);
  // 7. CA kv (wk|wv = ca_in_w rows 512..1535)
  gemm_k2<false, false, false><<<4608, 256, 0, stream>>>(
      x_bf, 512, ca_in_bf + 262144, ca_in_b + 512, nullptr, nullptr, 0, qkv, 73728, 1024, 512, 8);
  // 8. CA attention
  ca_attn_k<<<8192, 256, 0, stream>>>(q_bf, qkv, cattn);
  // 9. CA out proj + residual(cq) -> csum
  gemm_k2<false, true, false><<<256, 256, 0, stream>>>(
      cattn, 512, ca_out_bf, ca_out_b, nullptr, x_bf + 2048, 4608, csum, 8192, 512, 512, 4);
  // 10. LN2 (in place) -> c
  ln_k<<<8192 / 4, 256, 0, stream>>>(csum, g2, beta2, csum, nullptr, 8192);
  // 11. FFN1 + exact GELU -> h_bf
  gemm_k2<false, false, true><<<1024, 256, 0, stream>>>(
      csum, 512, w1_bf, b1, nullptr, nullptr, 0, h_bf, 8192, 2048, 512, 16);
  // 12. FFN2 + residual(c) -> osum
  gemm_k2<false, true, false><<<256, 256, 0, stream>>>(
      h_bf, 2048, w2_bf, b2, nullptr, csum, 512, osum, 8192, 512, 2048, 4);
  // 13. LN3 -> d_out (f32)
  ln_k<<<8192 / 4, 256, 0, stream>>>(osum, g3, beta3, nullptr, out, 8192);
}